// Round 7
// baseline (227.860 us; speedup 1.0000x reference)
//
#include <hip/hip_runtime.h>

#define IC 3
#define OCH 16
#define IDD 16
#define IHH 32
#define IWW 32
#define ODD 31
#define OHH 63
#define OWW 63
#define NB 32

typedef float f2 __attribute__((ext_vector_type(2)));

#define LOG2E 1.44269504088896340736f
#define LN2   0.69314718055994530942f

static __device__ __forceinline__ f2 fma2(f2 a, f2 b, f2 c) {
    return __builtin_elementwise_fma(a, b, c);   // -> v_pk_fma_f32
}
static __device__ __forceinline__ f2 bc(float s) { f2 r; r.x = s; r.y = s; return r; }

// Fused ConvTranspose3d(3->16,k3,s2,p1) + channel-LSE + x*sigmoid(x+3)/6 - bias, clip [-1,1].
// LDS-issue-bound diagnosis (rounds 0/4/6 all fit ~9.6-11.3 cyc/b128 saturated broadcast pipe):
// each weight ds_read must feed MORE pixels. This version: 8 pixels/thread (2 ow-pairs x
// 1 oh-pair), weights read ONCE per (ic,kd,oc-half) and reused across both pairs -> ds/pixel
// halved vs round-6. Register discipline: oc in 2 sequential chunks (#pragma unroll 1, acc
// scoped inside, sched_barrier between), f2 weight temps only, x loaded per-ic (L2-hot on
// chunk 2), macro-only acc access, __launch_bounds__(256,4) caps regalloc at 128 VGPR.
__global__ __launch_bounds__(256, 4) void convt_lse_kernel(
    const float* __restrict__ x, const float* __restrict__ w,
    const float* __restrict__ bias, float* __restrict__ out)
{
    __shared__ __align__(16) float wl[IC * 27 * OCH];

    const int jj = threadIdx.x & 15;                        // ow quad: ow = 4jj..4jj+3
    const int i  = (threadIdx.x >> 4) + (blockIdx.x << 4);  // oh pair: oh = 2i, 2i+1
    const int od = blockIdx.y;                              // [0,31)
    const int b  = blockIdx.z;                              // [0,32)

    const int r0 = i * IWW;
    const int r1 = min(i + 1, IHH - 1) * IWW;  // clamp: feeds only guarded oh=63
    const int c0 = 2 * jj;
    const int c1 = 2 * jj + 1;
    const int c2 = min(2 * jj + 2, IWW - 1);   // clamp: feeds only guarded ow=63

    const bool odd = (od & 1) != 0;
    const int id0 = odd ? ((od + 1) >> 1) : (od >> 1);
    const int id1 = (od - 1) >> 1;             // used only when odd

    // ---- stage weights (exp2 domain): wl[((ic*3+kd)*9 + kh*3+kw)*16 + oc]
    for (int idx = threadIdx.x; idx < IC * 27 * OCH; idx += 256) {
        int ic   = idx / (27 * OCH);
        int rem  = idx - ic * (27 * OCH);
        int kpos = rem >> 4;
        int oc   = rem & 15;
        wl[idx] = w[(ic * OCH + oc) * 27 + kpos] * LOG2E;
    }
    __syncthreads();

    const float bv = bias[0];

    // running sum-of-exp2 per pixel; px = q*4+p, q = ow-pair (A=4jj, B=4jj+2),
    // p: 0=(even oh,even ow) 1=(eo) 2=(oe) 3=(oo)
    float ss[8];
    #pragma unroll
    for (int px = 0; px < 8; ++px) ss[px] = 0.0f;

// One (ic,kd) tap for BOTH ow-pairs, one oc-half. X00..X12: x[r0|r1][c0|c1|c2].
// Pair A uses cols (c0,c1); pair B uses (c1,c2). 18 pk-fma per 9 f2 weight loads.
#define EMIT(first, X00, X01, X02, X10, X11, X12, wp2, cb)                            \
    {                                                                                 \
        _Pragma("unroll")                                                             \
        for (int q = 0; q < 4; ++q) {                                                 \
            const f2 w0 = wp2[0 * 8 + (cb) * 4 + q], w1 = wp2[1 * 8 + (cb) * 4 + q],  \
                     w2 = wp2[2 * 8 + (cb) * 4 + q], w3 = wp2[3 * 8 + (cb) * 4 + q],  \
                     w4 = wp2[4 * 8 + (cb) * 4 + q], w5 = wp2[5 * 8 + (cb) * 4 + q],  \
                     w6 = wp2[6 * 8 + (cb) * 4 + q], w7 = wp2[7 * 8 + (cb) * 4 + q],  \
                     w8 = wp2[8 * 8 + (cb) * 4 + q];                                  \
            if (first) {                                                              \
                acc[0][q] = bc(X00) * w4;                                             \
                acc[1][q] = bc(X01) * w3;                                             \
                acc[2][q] = bc(X10) * w1;                                             \
                acc[3][q] = bc(X11) * w0;                                             \
                acc[4][q] = bc(X01) * w4;                                             \
                acc[5][q] = bc(X02) * w3;                                             \
                acc[6][q] = bc(X11) * w1;                                             \
                acc[7][q] = bc(X12) * w0;                                             \
            } else {                                                                  \
                acc[0][q] = fma2(bc(X00), w4, acc[0][q]);                             \
                acc[1][q] = fma2(bc(X01), w3, acc[1][q]);                             \
                acc[2][q] = fma2(bc(X10), w1, acc[2][q]);                             \
                acc[3][q] = fma2(bc(X11), w0, acc[3][q]);                             \
                acc[4][q] = fma2(bc(X01), w4, acc[4][q]);                             \
                acc[5][q] = fma2(bc(X02), w3, acc[5][q]);                             \
                acc[6][q] = fma2(bc(X11), w1, acc[6][q]);                             \
                acc[7][q] = fma2(bc(X12), w0, acc[7][q]);                             \
            }                                                                         \
            acc[1][q] = fma2(bc(X00), w5, acc[1][q]);                                 \
            acc[2][q] = fma2(bc(X00), w7, acc[2][q]);                                 \
            acc[3][q] = fma2(bc(X10), w2, acc[3][q]);                                 \
            acc[3][q] = fma2(bc(X01), w6, acc[3][q]);                                 \
            acc[3][q] = fma2(bc(X00), w8, acc[3][q]);                                 \
            acc[5][q] = fma2(bc(X01), w5, acc[5][q]);                                 \
            acc[6][q] = fma2(bc(X01), w7, acc[6][q]);                                 \
            acc[7][q] = fma2(bc(X11), w2, acc[7][q]);                                 \
            acc[7][q] = fma2(bc(X02), w6, acc[7][q]);                                 \
            acc[7][q] = fma2(bc(X01), w8, acc[7][q]);                                 \
        }                                                                             \
    }

    #pragma unroll 1     // sequential oc-halves: ONE acc copy live (rounds 2/3/5 lesson)
    for (int chunk = 0; chunk < 2; ++chunk) {
        f2 acc[8][4];    // 8 pixels x 4 oc-pairs (this half) = 64 VGPR

        #pragma unroll
        for (int ic = 0; ic < IC; ++ic) {
            const float* __restrict__ xpA = x + (((b * IC + ic) * IDD + id0) << 10);
            const float a00 = xpA[r0 + c0], a01 = xpA[r0 + c1], a02 = xpA[r0 + c2];
            const float a10 = xpA[r1 + c0], a11 = xpA[r1 + c1], a12 = xpA[r1 + c2];
            if (odd) {   // kd=0 @ id0=(od+1)/2, kd=2 @ id1=(od-1)/2
                const float* __restrict__ xpB = x + (((b * IC + ic) * IDD + id1) << 10);
                const float e00 = xpB[r0 + c0], e01 = xpB[r0 + c1], e02 = xpB[r0 + c2];
                const float e10 = xpB[r1 + c0], e11 = xpB[r1 + c1], e12 = xpB[r1 + c2];
                const f2* __restrict__ wpa = (const f2*)(wl + (ic * 3 + 0) * 9 * OCH);
                const f2* __restrict__ wpb = (const f2*)(wl + (ic * 3 + 2) * 9 * OCH);
                EMIT(ic == 0, a00, a01, a02, a10, a11, a12, wpa, chunk)
                EMIT(false,   e00, e01, e02, e10, e11, e12, wpb, chunk)
            } else {     // kd=1 @ id0=od/2
                const f2* __restrict__ wpc = (const f2*)(wl + (ic * 3 + 1) * 9 * OCH);
                EMIT(ic == 0, a00, a01, a02, a10, a11, a12, wpc, chunk)
            }
        }

        // fold this half's exp2 into running sums (log2-domain acc; no max-sub: |acc|<=~9)
        #pragma unroll
        for (int px = 0; px < 8; ++px) {
            f2 e0, e1, e2, e3;
            e0.x = __builtin_amdgcn_exp2f(acc[px][0].x);
            e0.y = __builtin_amdgcn_exp2f(acc[px][0].y);
            e1.x = __builtin_amdgcn_exp2f(acc[px][1].x);
            e1.y = __builtin_amdgcn_exp2f(acc[px][1].y);
            e2.x = __builtin_amdgcn_exp2f(acc[px][2].x);
            e2.y = __builtin_amdgcn_exp2f(acc[px][2].y);
            e3.x = __builtin_amdgcn_exp2f(acc[px][3].x);
            e3.y = __builtin_amdgcn_exp2f(acc[px][3].y);
            const f2 t = (e0 + e1) + (e2 + e3);
            ss[px] += t.x + t.y;
        }
        __builtin_amdgcn_sched_barrier(0);   // no cross-chunk live-range merge
    }

    const int oh0   = 2 * i;
    const int ow0   = 4 * jj;
    const int obase = (b * ODD + od) * OHH;

    #pragma unroll
    for (int q = 0; q < 2; ++q)
        #pragma unroll
        for (int p = 0; p < 4; ++p) {
            const int px = q * 4 + p;
            const int oh = oh0 + (p >> 1);
            const int ow = ow0 + 2 * q + (p & 1);
            if (oh < OHH && ow < OWW) {
                const float S = ss[px];
                const float v = LN2 * __builtin_amdgcn_logf(S);          // ln(S)
                // v / (6*(1+exp(-(v+3)))), exp via exp2(fma), fast rcp
                const float t   = __builtin_amdgcn_exp2f(fmaf(-LOG2E, v, -3.0f * LOG2E));
                const float den = fmaf(6.0f, t, 6.0f);
                const float hs  = v * __builtin_amdgcn_rcpf(den);
                const float r   = fminf(1.0f, fmaxf(-1.0f, hs - bv));
                out[(obase + oh) * OWW + ow] = r;
            }
        }
}

extern "C" void kernel_launch(void* const* d_in, const int* in_sizes, int n_in,
                              void* d_out, int out_size, void* d_ws, size_t ws_size,
                              hipStream_t stream) {
    const float* x    = (const float*)d_in[0];
    const float* w    = (const float*)d_in[1];
    const float* bias = (const float*)d_in[2];
    float* out        = (float*)d_out;

    dim3 grid(2, ODD, NB);   // 2 i-chunks (16 i-values) x od x batch = 1984 blocks
    dim3 block(256);
    convt_lse_kernel<<<grid, block, 0, stream>>>(x, w, bias, out);
}

// Round 8
// 86.743 us; speedup vs baseline: 2.6268x; 2.6268x over previous
//
#include <hip/hip_runtime.h>

#define IC 3
#define OCH 16
#define IDD 16
#define IHH 32
#define IWW 32
#define ODD 31
#define OHH 63
#define OWW 63
#define NB 32

typedef float f2 __attribute__((ext_vector_type(2)));
typedef float f4 __attribute__((ext_vector_type(4)));

#define LOG2E 1.44269504088896340736f
#define LN2   0.69314718055994530942f

static __device__ __forceinline__ f2 fma2(f2 a, f2 b, f2 c) {
    return __builtin_elementwise_fma(a, b, c);   // -> v_pk_fma_f32
}

// ---- kernel A: one-time weight transpose into workspace -------------------------
// wt[((ic*3+kd)*9 + kh*3+kw)*16 + oc] = w[(ic*16+oc)*27 + kd*9+kh*3+kw] * log2(e)
__global__ void wprep_kernel(const float* __restrict__ w, float* __restrict__ wt) {
    int idx = threadIdx.x + blockIdx.x * 256;
    if (idx < IC * 27 * OCH) {
        int ic   = idx / (27 * OCH);
        int rem  = idx - ic * (27 * OCH);
        int kpos = rem >> 4;
        int oc   = rem & 15;
        wt[idx] = w[(ic * OCH + oc) * 27 + kpos] * LOG2E;
    }
}

// ---- main kernel ----------------------------------------------------------------
// Fused ConvTranspose3d(3->16,k3,s2,p1) + channel-LSE + x*sigmoid(x+3)/6 - bias, clip [-1,1].
// Round-4's proven straight-line shape (2x2 patch/thread, one od, packed-f2 acc, macro-only
// access). NEW: no LDS, no staging, no __syncthreads. Weights come from the pre-transposed
// 5 KB table in d_ws via wave-uniform global f4 loads -> one L1 transaction broadcast to all
// lanes; table is L1-resident after each CU's first block. Removes the barrier convoy and
// moves weight reads off the LDS pipe onto the idle VMEM path.
__global__ __launch_bounds__(256, 4) void convt_lse_kernel(
    const float* __restrict__ x, const float* __restrict__ wt,
    const float* __restrict__ bias, float* __restrict__ out)
{
    const int j  = threadIdx.x & 31;                       // ow pair: ow = 2j, 2j+1
    const int i  = (threadIdx.x >> 5) + (blockIdx.x << 3); // oh pair: oh = 2i, 2i+1
    const int od = blockIdx.y;
    const int b  = blockIdx.z;

    const int ih0 = i;
    const int ih1 = min(i + 1, IHH - 1);   // clamp: feeds only non-stored oh=63
    const int iw0 = j;
    const int iw1 = min(j + 1, IWW - 1);   // clamp: feeds only non-stored ow=63

    const bool odd = (od & 1) != 0;
    const int id0 = odd ? ((od + 1) >> 1) : (od >> 1);
    const int id1 = (od - 1) >> 1;         // used only when odd

    // x loads issued first; vmcnt waits land inside the FMA stream
    float xr[2][IC][4];    // [tap][ic][{00,01,10,11}] - compile-time indexed only
    #pragma unroll
    for (int ic = 0; ic < IC; ++ic) {
        const float* __restrict__ xp = x + (((b * IC + ic) * IDD + id0) << 10);
        xr[0][ic][0] = xp[ih0 * IWW + iw0];
        xr[0][ic][1] = xp[ih0 * IWW + iw1];
        xr[0][ic][2] = xp[ih1 * IWW + iw0];
        xr[0][ic][3] = xp[ih1 * IWW + iw1];
    }
    if (odd) {
        #pragma unroll
        for (int ic = 0; ic < IC; ++ic) {
            const float* __restrict__ xp = x + (((b * IC + ic) * IDD + id1) << 10);
            xr[1][ic][0] = xp[ih0 * IWW + iw0];
            xr[1][ic][1] = xp[ih0 * IWW + iw1];
            xr[1][ic][2] = xp[ih1 * IWW + iw0];
            xr[1][ic][3] = xp[ih1 * IWW + iw1];
        }
    }
    const float bv = bias[0];

    // acc[p][cp]: p 0=(ee) 1=(eo) 2=(oe) 3=(oo); cp = oc pair (2 channels)
    f2 acc[4][8];

// 9 f4 weight loads (wave-uniform addr -> L1 broadcast) feeding 18 pk-fma per (ic,q)
#define TAPQ(first, x00, x01, x10, x11, wq)                                           \
    {                                                                                 \
        _Pragma("unroll")                                                             \
        for (int q = 0; q < 4; ++q) {                                                 \
            const f4 W0 = wq[0 * 4 + q], W1 = wq[1 * 4 + q], W2 = wq[2 * 4 + q],      \
                     W3 = wq[3 * 4 + q], W4 = wq[4 * 4 + q], W5 = wq[5 * 4 + q],      \
                     W6 = wq[6 * 4 + q], W7 = wq[7 * 4 + q], W8 = wq[8 * 4 + q];      \
            _Pragma("unroll")                                                         \
            for (int h = 0; h < 2; ++h) {                                             \
                const int cp = 2 * q + h;                                             \
                const f2 w0 = {W0[2*h], W0[2*h+1]}, w1 = {W1[2*h], W1[2*h+1]},        \
                         w2 = {W2[2*h], W2[2*h+1]}, w3 = {W3[2*h], W3[2*h+1]},        \
                         w4 = {W4[2*h], W4[2*h+1]}, w5 = {W5[2*h], W5[2*h+1]},        \
                         w6 = {W6[2*h], W6[2*h+1]}, w7 = {W7[2*h], W7[2*h+1]},        \
                         w8 = {W8[2*h], W8[2*h+1]};                                   \
                if (first) {                                                          \
                    acc[3][cp] = x11 * w0;                                            \
                    acc[2][cp] = x10 * w1;                                            \
                    acc[1][cp] = x01 * w3;                                            \
                    acc[0][cp] = x00 * w4;                                            \
                } else {                                                              \
                    acc[3][cp] = fma2(x11, w0, acc[3][cp]);                           \
                    acc[2][cp] = fma2(x10, w1, acc[2][cp]);                           \
                    acc[1][cp] = fma2(x01, w3, acc[1][cp]);                           \
                    acc[0][cp] = fma2(x00, w4, acc[0][cp]);                           \
                }                                                                     \
                acc[3][cp] = fma2(x10, w2, acc[3][cp]);                               \
                acc[1][cp] = fma2(x00, w5, acc[1][cp]);                               \
                acc[3][cp] = fma2(x01, w6, acc[3][cp]);                               \
                acc[2][cp] = fma2(x00, w7, acc[2][cp]);                               \
                acc[3][cp] = fma2(x00, w8, acc[3][cp]);                               \
            }                                                                         \
        }                                                                             \
    }

#define DO_TAP(kd, tpi, first)                                                        \
    {                                                                                 \
        _Pragma("unroll")                                                             \
        for (int ic = 0; ic < IC; ++ic) {                                             \
            const f2 x00 = {xr[tpi][ic][0], xr[tpi][ic][0]};                          \
            const f2 x01 = {xr[tpi][ic][1], xr[tpi][ic][1]};                          \
            const f2 x10 = {xr[tpi][ic][2], xr[tpi][ic][2]};                          \
            const f2 x11 = {xr[tpi][ic][3], xr[tpi][ic][3]};                          \
            const f4* __restrict__ wq = (const f4*)(wt + (ic * 3 + (kd)) * 9 * OCH);  \
            TAPQ((first) && ic == 0, x00, x01, x10, x11, wq)                          \
        }                                                                             \
    }

    if (odd) {          // odd od: kd=0 @ id0=(od+1)/2, kd=2 @ id1=(od-1)/2
        DO_TAP(0, 0, true)
        DO_TAP(2, 1, false)
    } else {            // even od: kd=1 @ id0=od/2
        DO_TAP(1, 0, true)
    }

    const int oh0   = 2 * i;
    const int ow0   = 2 * j;
    const int obase = (b * ODD + od) * OHH;

    #pragma unroll
    for (int p = 0; p < 4; ++p) {
        const int oh = oh0 + (p >> 1);
        const int ow = ow0 + (p & 1);
        if (oh < OHH && ow < OWW) {
            // acc is log2-domain: S = sum exp2(acc); no max-sub (|acc| bounded << 126)
            f2 sa = {0.0f, 0.0f}, sb = {0.0f, 0.0f};
            #pragma unroll
            for (int cp = 0; cp < 8; cp += 2) {
                f2 ea, eb;
                ea.x = __builtin_amdgcn_exp2f(acc[p][cp].x);
                ea.y = __builtin_amdgcn_exp2f(acc[p][cp].y);
                eb.x = __builtin_amdgcn_exp2f(acc[p][cp + 1].x);
                eb.y = __builtin_amdgcn_exp2f(acc[p][cp + 1].y);
                sa += ea;                       // v_pk_add_f32
                sb += eb;
            }
            const f2 st   = sa + sb;
            const float S = st.x + st.y;
            const float v = LN2 * __builtin_amdgcn_logf(S);          // ln(S)
            // v / (6*(1+exp(-(v+3)))), exp via exp2(fma), fast rcp
            const float t   = __builtin_amdgcn_exp2f(fmaf(-LOG2E, v, -3.0f * LOG2E));
            const float den = fmaf(6.0f, t, 6.0f);
            const float hs  = v * __builtin_amdgcn_rcpf(den);
            const float r   = fminf(1.0f, fmaxf(-1.0f, hs - bv));
            out[(obase + oh) * OWW + ow] = r;
        }
    }
}

extern "C" void kernel_launch(void* const* d_in, const int* in_sizes, int n_in,
                              void* d_out, int out_size, void* d_ws, size_t ws_size,
                              hipStream_t stream) {
    const float* x    = (const float*)d_in[0];
    const float* w    = (const float*)d_in[1];
    const float* bias = (const float*)d_in[2];
    float* out        = (float*)d_out;
    float* wt         = (float*)d_ws;     // 1296 floats = 5.2 KB scratch

    wprep_kernel<<<dim3(6), dim3(256), 0, stream>>>(w, wt);

    dim3 grid(4, ODD, NB);   // 4 i-chunks (8 i-values each) x od x batch
    dim3 block(256);
    convt_lse_kernel<<<grid, block, 0, stream>>>(x, wt, bias, out);
}